// Round 2
// baseline (289.579 us; speedup 1.0000x reference)
//
#include <hip/hip_runtime.h>

typedef unsigned short u16;
typedef unsigned int u32;
typedef __bf16 bf16x8 __attribute__((ext_vector_type(8)));
typedef float f32x4 __attribute__((ext_vector_type(4)));
typedef u16 u16x8 __attribute__((ext_vector_type(8)));

#define BB 4
#define NQ 4096
#define NKV 1024
#define QD 512
#define CD 768
#define NH 8
#define DH 64
#define DI 512

__device__ __forceinline__ u16 f2bf(float f) {
    u32 u = __float_as_uint(f);
    u = (u + 0x7fffu + ((u >> 16) & 1u)) >> 16;
    return (u16)u;
}

__device__ __forceinline__ u32 cvtpk(float lo, float hi) {
    u32 r;
    asm("v_cvt_pk_bf16_f32 %0, %1, %2" : "=v"(r) : "v"(lo), "v"(hi));
    return r;
}

__device__ __forceinline__ void gload16(const void* g, void* l) {
    __builtin_amdgcn_global_load_lds(
        (const __attribute__((address_space(1))) u32*)g,
        (__attribute__((address_space(3))) u32*)l, 16, 0, 0);
}

__device__ __forceinline__ f32x4 MFMA(bf16x8 a, bf16x8 b, f32x4 c) {
    return __builtin_amdgcn_mfma_f32_16x16x32_bf16(a, b, c, 0, 0, 0);
}

// ---------- f32 -> bf16 elementwise (8 elems/thread) ----------
__global__ __launch_bounds__(256)
void k_conv(const float* __restrict__ in, u16* __restrict__ out, int n8) {
    int i = blockIdx.x * 256 + threadIdx.x;
    if (i >= n8) return;
    float4 u0 = ((const float4*)in)[2 * i];
    float4 u1 = ((const float4*)in)[2 * i + 1];
    uint4 v;
    v.x = cvtpk(u0.x, u0.y);
    v.y = cvtpk(u0.z, u0.w);
    v.z = cvtpk(u1.x, u1.y);
    v.w = cvtpk(u1.z, u1.w);
    ((uint4*)out)[i] = v;
}

// ---------- weight transpose + f32->bf16: Wt[n][k] = bf16(W[k][n]) ----------
__global__ __launch_bounds__(256)
void k_transposeW(const float* __restrict__ W, u16* __restrict__ Wt, int K, int N) {
    __shared__ float tile[32][33];
    int kb = blockIdx.x * 32, nb = blockIdx.y * 32;
    int tx = threadIdx.x & 31, ty = threadIdx.x >> 5;
    for (int i = ty; i < 32; i += 8)
        tile[i][tx] = W[(size_t)(kb + i) * N + nb + tx];
    __syncthreads();
    for (int i = ty; i < 32; i += 8)
        Wt[(size_t)(nb + i) * K + kb + tx] = f2bf(tile[tx][i]);
}

// ---------- V transpose: Vt[(bh*64+d)*NKV + j] = KV[(b*NKV+j)*1024 + 512 + h*64 + d] ----------
__global__ __launch_bounds__(256)
void k_transposeV(const u16* __restrict__ KV, u16* __restrict__ Vt) {
    __shared__ u16 tile[32][33];
    int j0 = blockIdx.x * 32, d0 = blockIdx.y * 32, bh = blockIdx.z;
    int b = bh >> 3, h = bh & 7;
    int tx = threadIdx.x & 31, ty = threadIdx.x >> 5;
    for (int i = ty; i < 32; i += 8)
        tile[i][tx] = KV[(size_t)(b * NKV + j0 + i) * 1024 + 512 + h * DH + d0 + tx];
    __syncthreads();
    for (int i = ty; i < 32; i += 8)
        Vt[(size_t)(bh * DH + d0 + i) * NKV + j0 + tx] = tile[tx][i];
}

// ---------- GEMM: C[M][N] = A[M][K] @ Bt[N][K]^T (+bias), 128x128, BK=64,
// global_load_lds staging w/ pre-swizzled source, XOR-swizzled LDS reads ----------
template <bool OUTF32, bool BIAS>
__global__ __launch_bounds__(256, 2)
void k_gemm(const u16* __restrict__ A, const u16* __restrict__ Bt,
            void* __restrict__ Cv, const float* __restrict__ bias,
            int M, int N, int K) {
    __shared__ u16 lA[128 * 64];
    __shared__ u16 lB[128 * 64];
    const int t = threadIdx.x;
    const int w = t >> 6, lane = t & 63, r = lane & 15, g = lane >> 4;
    const int m0 = blockIdx.x * 128, n0 = blockIdx.y * 128;
    const int wm = (w >> 1) * 64, wn = (w & 1) * 64;

    // staging geometry: per wave-call, LDS gets 1KB linear; row = w*32 + c*8 + (lane>>3)
    // source slot is permuted so swizzled reads see layout byte = (row<<7|ch<<4) ^ ((row&7)<<4)
    const int rsub = lane >> 3;
    const int slot = (lane & 7) ^ rsub;
    const u16* gA = A + (size_t)(m0 + w * 32 + rsub) * K + slot * 8;
    const u16* gB = Bt + (size_t)(n0 + w * 32 + rsub) * K + slot * 8;
    u16* lAw = lA + w * 2048;
    u16* lBw = lB + w * 2048;

    f32x4 acc[4][4];
#pragma unroll
    for (int a = 0; a < 4; ++a)
#pragma unroll
        for (int c = 0; c < 4; ++c) acc[a][c] = {};

#pragma unroll 1
    for (int kt = 0; kt < K; kt += 64) {
        __syncthreads();
#pragma unroll
        for (int c = 0; c < 4; ++c) {
            gload16(gA + (size_t)(c * 8) * K + kt, lAw + c * 512);
            gload16(gB + (size_t)(c * 8) * K + kt, lBw + c * 512);
        }
        __syncthreads();
#pragma unroll
        for (int ks = 0; ks < 2; ++ks) {
            bf16x8 af[4], bfr[4];
#pragma unroll
            for (int mt = 0; mt < 4; ++mt) {
                int row = wm + mt * 16 + r;
                int byte = ((row << 7) | (ks << 6) | (g << 4)) ^ ((row & 7) << 4);
                af[mt] = *(const bf16x8*)((const char*)lA + byte);
            }
#pragma unroll
            for (int nt = 0; nt < 4; ++nt) {
                int row = wn + nt * 16 + r;
                int byte = ((row << 7) | (ks << 6) | (g << 4)) ^ ((row & 7) << 4);
                bfr[nt] = *(const bf16x8*)((const char*)lB + byte);
            }
#pragma unroll
            for (int mt = 0; mt < 4; ++mt)
#pragma unroll
                for (int nt = 0; nt < 4; ++nt)
                    acc[mt][nt] = MFMA(af[mt], bfr[nt], acc[mt][nt]);
        }
    }
#pragma unroll
    for (int mt = 0; mt < 4; ++mt) {
#pragma unroll
        for (int i = 0; i < 4; ++i) {
            int row = m0 + wm + mt * 16 + g * 4 + i;
#pragma unroll
            for (int nt = 0; nt < 4; ++nt) {
                int col = n0 + wn + nt * 16 + r;
                float vv = acc[mt][nt][i];
                if constexpr (BIAS) vv += bias[col];
                if constexpr (OUTF32) ((float*)Cv)[(size_t)row * N + col] = vv;
                else ((u16*)Cv)[(size_t)row * N + col] = f2bf(vv);
            }
        }
    }
}

// ---------- flash attention, zero-LDS, barrier-free ----------
// Q[b*NQ][512], KV[b*NKV][1024] (K = cols 0..511), Vt[(bh*64+d)][NKV] -> O[b*NQ][512]
// per wave: 32 q-rows (2 x 16). Swapped QK^T: st = mfma(K, Q) -> lane(r,g) holds
// S[q-row = blk+r][j = 16jt + 4g + ii]. PV A-frag built in-register via
// cvt_pk_bf16 + permlane32_swap/permlane16_swap (D0..D3 word derivation).
__global__ __launch_bounds__(256, 3)
void k_attn(const u16* __restrict__ Q, const u16* __restrict__ KV,
            const u16* __restrict__ Vt, u16* __restrict__ O) {
    const int t = threadIdx.x;
    const int w = t >> 6, lane = t & 63, r = lane & 15, g = lane >> 4;
    const int bh = blockIdx.x, qt = blockIdx.y;   // bh on x => same-XCD KV locality
    const int b = bh >> 3, h = bh & 7;
    const int q0 = qt * 128 + w * 32;

    const u16* Kbase = KV + (size_t)b * NKV * 1024 + h * DH;
    const u16* Vbase = Vt + (size_t)bh * DH * NKV;

    bf16x8 qf[2][2];
#pragma unroll
    for (int itl = 0; itl < 2; ++itl) {
        const u16* qp = Q + (size_t)(b * NQ + q0 + itl * 16 + r) * DI + h * DH;
#pragma unroll
        for (int ks = 0; ks < 2; ++ks)
            qf[itl][ks] = *(const bf16x8*)(qp + ks * 32 + g * 8);
    }

    float mrow[2] = {-3e38f, -3e38f};
    float lrow[2] = {0.f, 0.f};
    f32x4 oacc[2][4];
#pragma unroll
    for (int a = 0; a < 2; ++a)
#pragma unroll
        for (int c = 0; c < 4; ++c) oacc[a][c] = {};

    const float c1 = 0.125f * 1.44269504f;  // scale * log2(e)

#pragma unroll 1
    for (int kv0 = 0; kv0 < NKV; kv0 += 128) {
        // ---- QK^T (swapped): K direct-from-global as A-operand ----
        f32x4 st[8][2];
#pragma unroll
        for (int jt = 0; jt < 8; ++jt) {
            const u16* kp = Kbase + (size_t)(kv0 + jt * 16 + r) * 1024;
            bf16x8 k0 = *(const bf16x8*)(kp + g * 8);
            bf16x8 k1 = *(const bf16x8*)(kp + 32 + g * 8);
#pragma unroll
            for (int itl = 0; itl < 2; ++itl) {
                f32x4 a = {};
                a = MFMA(k0, qf[itl][0], a);
                a = MFMA(k1, qf[itl][1], a);
                st[jt][itl] = a;
            }
        }

        // ---- tile max (log2 domain), defer-max rescale ----
        float pmax[2], corr[2] = {1.f, 1.f};
#pragma unroll
        for (int itl = 0; itl < 2; ++itl) {
            float mx = st[0][itl][0];
#pragma unroll
            for (int jt = 0; jt < 8; ++jt)
#pragma unroll
                for (int ii = 0; ii < 4; ++ii) mx = fmaxf(mx, st[jt][itl][ii]);
            mx = fmaxf(mx, __shfl_xor(mx, 16));
            mx = fmaxf(mx, __shfl_xor(mx, 32));
            pmax[itl] = mx * c1;
        }
        if (!__all(pmax[0] <= mrow[0] + 11.f && pmax[1] <= mrow[1] + 11.f)) {
#pragma unroll
            for (int itl = 0; itl < 2; ++itl) {
                float mnew = fmaxf(mrow[itl], pmax[itl]);
                corr[itl] = __builtin_amdgcn_exp2f(mrow[itl] - mnew);
                mrow[itl] = mnew;
            }
#pragma unroll
            for (int mtl = 0; mtl < 2; ++mtl)
#pragma unroll
                for (int ii = 0; ii < 4; ++ii) {
                    float c = __shfl(corr[mtl], g * 4 + ii);
#pragma unroll
                    for (int nt = 0; nt < 4; ++nt) oacc[mtl][nt][ii] *= c;
                }
        }

        // ---- exp + pack + permlane transpose + PV ----
        float tsum[2] = {0.f, 0.f};
#pragma unroll
        for (int ks = 0; ks < 4; ++ks) {
            bf16x8 vf[4];
#pragma unroll
            for (int nt = 0; nt < 4; ++nt)
                vf[nt] = *(const bf16x8*)(Vbase + (size_t)(nt * 16 + r) * NKV + kv0 + ks * 32 + g * 8);
            bf16x8 pa[2];
#pragma unroll
            for (int itl = 0; itl < 2; ++itl) {
                float e[8];
#pragma unroll
                for (int ii = 0; ii < 4; ++ii) {
                    e[ii]     = __builtin_amdgcn_exp2f(st[2 * ks][itl][ii] * c1 - mrow[itl]);
                    e[4 + ii] = __builtin_amdgcn_exp2f(st[2 * ks + 1][itl][ii] * c1 - mrow[itl]);
                }
#pragma unroll
                for (int ii = 0; ii < 8; ++ii) tsum[itl] += e[ii];
                u32 a0 = cvtpk(e[0], e[1]), a1 = cvtpk(e[2], e[3]);
                u32 b0 = cvtpk(e[4], e[5]), b1 = cvtpk(e[6], e[7]);
                // (A0,B0) -> (D0, D2); (A1,B1) -> (D1, D3)
                asm("v_permlane32_swap_b32 %0, %1" : "+v"(a0), "+v"(b0));
                asm("v_permlane16_swap_b32 %0, %1" : "+v"(a0), "+v"(b0));
                asm("v_permlane32_swap_b32 %0, %1" : "+v"(a1), "+v"(b1));
                asm("v_permlane16_swap_b32 %0, %1" : "+v"(a1), "+v"(b1));
                union { u32 u[4]; bf16x8 v; } pk;
                pk.u[0] = a0; pk.u[1] = a1; pk.u[2] = b0; pk.u[3] = b1;
                pa[itl] = pk.v;
            }
#pragma unroll
            for (int mtl = 0; mtl < 2; ++mtl)
#pragma unroll
                for (int nt = 0; nt < 4; ++nt)
                    oacc[mtl][nt] = MFMA(pa[mtl], vf[nt], oacc[mtl][nt]);
        }
#pragma unroll
        for (int itl = 0; itl < 2; ++itl) {
            float s = tsum[itl];
            s += __shfl_xor(s, 16);
            s += __shfl_xor(s, 32);
            lrow[itl] = lrow[itl] * corr[itl] + s;
        }
    }

    // ---- normalize + store ----
#pragma unroll
    for (int mtl = 0; mtl < 2; ++mtl) {
#pragma unroll
        for (int ii = 0; ii < 4; ++ii) {
            float lv = __shfl(lrow[mtl], g * 4 + ii);
            float linv = __builtin_amdgcn_rcpf(lv);
            int i = q0 + mtl * 16 + g * 4 + ii;
#pragma unroll
            for (int nt = 0; nt < 4; ++nt) {
                int d = nt * 16 + r;
                O[(size_t)(b * NQ + i) * DI + h * DH + d] = f2bf(oacc[mtl][nt][ii] * linv);
            }
        }
    }
}

extern "C" void kernel_launch(void* const* d_in, const int* in_sizes, int n_in,
                              void* d_out, int out_size, void* d_ws, size_t ws_size,
                              hipStream_t stream) {
    (void)in_sizes; (void)n_in; (void)out_size; (void)ws_size;
    const float* x   = (const float*)d_in[0];
    const float* ctx = (const float*)d_in[1];
    const float* Wq  = (const float*)d_in[2];
    const float* Wk  = (const float*)d_in[3];
    const float* Wv  = (const float*)d_in[4];
    const float* Wo  = (const float*)d_in[5];
    const float* bo  = (const float*)d_in[6];
    float* out = (float*)d_out;

    char* ws = (char*)d_ws;
    u16* Wqt  = (u16*)(ws);                                  // 0.5 MB
    u16* Wkvt = (u16*)(ws + (size_t)524288);                 // 1.5 MB
    u16* Wot  = (u16*)(ws + (size_t)2097152);                // 0.5 MB
    u16* Qw   = (u16*)(ws + (size_t)2621440);                // 16 MB
    u16* KVw  = (u16*)(ws + (size_t)19398656);               // 8 MB
    u16* slotC = (u16*)(ws + (size_t)27787264);              // 16 MB: xb then Ow
    u16* slotD = (u16*)(ws + (size_t)44564480);              // 6 MB: ctxb then Vtw
    u16* xb   = slotC;
    u16* Ow   = slotC;
    u16* ctxb = slotD;
    u16* Vtw  = slotD;

    k_conv<<<dim3(4096), 256, 0, stream>>>(x, xb, BB * NQ * QD / 8);
    k_conv<<<dim3(1536), 256, 0, stream>>>(ctx, ctxb, BB * NKV * CD / 8);

    k_transposeW<<<dim3(16, 16), 256, 0, stream>>>(Wq, Wqt, 512, 512);
    k_transposeW<<<dim3(24, 16), 256, 0, stream>>>(Wk, Wkvt, 768, 512);
    k_transposeW<<<dim3(24, 16), 256, 0, stream>>>(Wv, Wkvt + (size_t)512 * 768, 768, 512);
    k_transposeW<<<dim3(16, 16), 256, 0, stream>>>(Wo, Wot, 512, 512);

    k_gemm<false, false><<<dim3(128, 4), 256, 0, stream>>>(xb, Wqt, Qw, nullptr, BB * NQ, DI, QD);
    k_gemm<false, false><<<dim3(32, 8), 256, 0, stream>>>(ctxb, Wkvt, KVw, nullptr, BB * NKV, 1024, CD);
    k_transposeV<<<dim3(32, 2, 32), 256, 0, stream>>>(KVw, Vtw);
    k_attn<<<dim3(32, 32), 256, 0, stream>>>(Qw, KVw, Vtw, Ow);
    k_gemm<true, true><<<dim3(128, 4), 256, 0, stream>>>(Ow, Wot, out, bo, BB * NQ, QD, DI);
}

// Round 3
// 203.247 us; speedup vs baseline: 1.4248x; 1.4248x over previous
//
#include <hip/hip_runtime.h>

typedef unsigned short u16;
typedef unsigned int u32;
typedef __bf16 bf16x8 __attribute__((ext_vector_type(8)));
typedef float f32x4 __attribute__((ext_vector_type(4)));
typedef u16 u16x8 __attribute__((ext_vector_type(8)));

#define BB 4
#define NQ 4096
#define NKV 1024
#define QD 512
#define CD 768
#define NH 8
#define DH 64
#define DI 512

__device__ __forceinline__ u16 f2bf(float f) {
    u32 u = __float_as_uint(f);
    u = (u + 0x7fffu + ((u >> 16) & 1u)) >> 16;
    return (u16)u;
}

__device__ __forceinline__ u32 cvtpk(float lo, float hi) {
    u32 r;
    asm("v_cvt_pk_bf16_f32 %0, %1, %2" : "=v"(r) : "v"(lo), "v"(hi));
    return r;
}

__device__ __forceinline__ void gload16(const void* g, void* l) {
    __builtin_amdgcn_global_load_lds(
        (const __attribute__((address_space(1))) u32*)g,
        (__attribute__((address_space(3))) u32*)l, 16, 0, 0);
}

__device__ __forceinline__ f32x4 MFMA(bf16x8 a, bf16x8 b, f32x4 c) {
    return __builtin_amdgcn_mfma_f32_16x16x32_bf16(a, b, c, 0, 0, 0);
}

// ---------- fused f32->bf16 for x and ctx (8 elems/thread) ----------
__global__ __launch_bounds__(256)
void k_conv2(const float* __restrict__ a, u16* __restrict__ ao, int n8a,
             const float* __restrict__ b, u16* __restrict__ bo, int n8b) {
    int i = blockIdx.x * 256 + threadIdx.x;
    const float* in; u16* out; int j;
    if (i < n8a) { in = a; out = ao; j = i; }
    else { j = i - n8a; if (j >= n8b) return; in = b; out = bo; }
    float4 u0 = ((const float4*)in)[2 * j];
    float4 u1 = ((const float4*)in)[2 * j + 1];
    uint4 v;
    v.x = cvtpk(u0.x, u0.y);
    v.y = cvtpk(u0.z, u0.w);
    v.z = cvtpk(u1.x, u1.y);
    v.w = cvtpk(u1.z, u1.w);
    ((uint4*)out)[j] = v;
}

// ---------- all 4 weight transposes in one launch: Wt[n][k] = bf16(W[k][n]) ----------
__global__ __launch_bounds__(256)
void k_transposeAll(const float* __restrict__ Wq, const float* __restrict__ Wk,
                    const float* __restrict__ Wv, const float* __restrict__ Wo,
                    u16* __restrict__ Wqt, u16* __restrict__ Wkvt, u16* __restrict__ Wot) {
    __shared__ float tile[32][33];
    const float* W; u16* Wt; int K, N;
    int z = blockIdx.z;
    if (z == 0)      { W = Wq; Wt = Wqt;                        K = 512; N = 512; }
    else if (z == 1) { W = Wk; Wt = Wkvt;                       K = 768; N = 512; }
    else if (z == 2) { W = Wv; Wt = Wkvt + (size_t)512 * 768;   K = 768; N = 512; }
    else             { W = Wo; Wt = Wot;                        K = 512; N = 512; }
    int kb = blockIdx.x * 32, nb = blockIdx.y * 32;
    if (kb >= K) return;
    int tx = threadIdx.x & 31, ty = threadIdx.x >> 5;
    for (int i = ty; i < 32; i += 8)
        tile[i][tx] = W[(size_t)(kb + i) * N + nb + tx];
    __syncthreads();
    for (int i = ty; i < 32; i += 8)
        Wt[(size_t)(nb + i) * K + kb + tx] = f2bf(tile[tx][i]);
}

// ---------- V transpose: Vt[(bh*64+d)*NKV + j] = KV[(b*NKV+j)*1024 + 512 + h*64 + d] ----------
__global__ __launch_bounds__(256)
void k_transposeV(const u16* __restrict__ KV, u16* __restrict__ Vt) {
    __shared__ u16 tile[32][33];
    int j0 = blockIdx.x * 32, d0 = blockIdx.y * 32, bh = blockIdx.z;
    int b = bh >> 3, h = bh & 7;
    int tx = threadIdx.x & 31, ty = threadIdx.x >> 5;
    for (int i = ty; i < 32; i += 8)
        tile[i][tx] = KV[(size_t)(b * NKV + j0 + i) * 1024 + 512 + h * DH + d0 + tx];
    __syncthreads();
    for (int i = ty; i < 32; i += 8)
        Vt[(size_t)(bh * DH + d0 + i) * NKV + j0 + tx] = tile[tx][i];
}

// ---------- GEMM: C[M][N] = A[M][K] @ Bt[N][K]^T (+bias), BM=64 BN=128 BK=64,
// global_load_lds staging, pre-swizzled source + XOR-swizzled ds_read ----------
template <bool OUTF32, bool BIAS>
__global__ __launch_bounds__(256, 4)
void k_gemm(const u16* __restrict__ A, const u16* __restrict__ Bt,
            void* __restrict__ Cv, const float* __restrict__ bias,
            int M, int N, int K) {
    __shared__ u16 lA[64 * 64];
    __shared__ u16 lB[128 * 64];
    const int t = threadIdx.x;
    const int w = t >> 6, lane = t & 63, r = lane & 15, g = lane >> 4;
    const int m0 = blockIdx.x * 64, n0 = blockIdx.y * 128;
    const int wm = (w >> 1) * 32, wn = (w & 1) * 64;

    const int rsub = lane >> 3;
    const int slot = (lane & 7) ^ rsub;
    const u16* gA = A + (size_t)(m0 + w * 8 + rsub) * K + slot * 8;
    const u16* gB = Bt + (size_t)(n0 + w * 8 + rsub) * K + slot * 8;

    f32x4 acc[2][4];
#pragma unroll
    for (int a = 0; a < 2; ++a)
#pragma unroll
        for (int c = 0; c < 4; ++c) acc[a][c] = {};

#pragma unroll 1
    for (int kt = 0; kt < K; kt += 64) {
        __syncthreads();
#pragma unroll
        for (int c = 0; c < 2; ++c)
            gload16(gA + (size_t)(c * 32) * K + kt, (char*)lA + c * 4096 + w * 1024);
#pragma unroll
        for (int c = 0; c < 4; ++c)
            gload16(gB + (size_t)(c * 32) * K + kt, (char*)lB + c * 4096 + w * 1024);
        __syncthreads();
#pragma unroll
        for (int ks = 0; ks < 2; ++ks) {
            bf16x8 af[2], bfr[4];
#pragma unroll
            for (int mt = 0; mt < 2; ++mt) {
                int row = wm + mt * 16 + r;
                int byte = ((row << 7) | (ks << 6) | (g << 4)) ^ ((row & 7) << 4);
                af[mt] = *(const bf16x8*)((const char*)lA + byte);
            }
#pragma unroll
            for (int nt = 0; nt < 4; ++nt) {
                int row = wn + nt * 16 + r;
                int byte = ((row << 7) | (ks << 6) | (g << 4)) ^ ((row & 7) << 4);
                bfr[nt] = *(const bf16x8*)((const char*)lB + byte);
            }
#pragma unroll
            for (int mt = 0; mt < 2; ++mt)
#pragma unroll
                for (int nt = 0; nt < 4; ++nt)
                    acc[mt][nt] = MFMA(af[mt], bfr[nt], acc[mt][nt]);
        }
    }
#pragma unroll
    for (int mt = 0; mt < 2; ++mt) {
#pragma unroll
        for (int i = 0; i < 4; ++i) {
            int row = m0 + wm + mt * 16 + g * 4 + i;
#pragma unroll
            for (int nt = 0; nt < 4; ++nt) {
                int col = n0 + wn + nt * 16 + r;
                float vv = acc[mt][nt][i];
                if constexpr (BIAS) vv += bias[col];
                if constexpr (OUTF32) ((float*)Cv)[(size_t)row * N + col] = vv;
                else ((u16*)Cv)[(size_t)row * N + col] = f2bf(vv);
            }
        }
    }
}

// ---------- flash attention: K/V LDS-staged (gload_lds + swizzle), P in-register ----------
// Q[b*NQ][512], KV[b*NKV][1024] (K cols 0..511), Vt[(bh*64+d)][NKV] -> O[b*NQ][512]
__global__ __launch_bounds__(256, 3)
void k_attn(const u16* __restrict__ Q, const u16* __restrict__ KV,
            const u16* __restrict__ Vt, u16* __restrict__ O) {
    __shared__ u16 lK[128 * 64];   // [j][d], 128B rows, XOR swizzle ((row&7)<<4)
    __shared__ u16 lV[64 * 128];   // [d][j], 256B rows, XOR swizzle ((row&7)<<4)
    const int t = threadIdx.x;
    const int w = t >> 6, lane = t & 63, r = lane & 15, g = lane >> 4;
    const int bh = blockIdx.x, qt = blockIdx.y;  // bh fastest => bh%8 fixes XCD, KV L2-local
    const int b = bh >> 3, h = bh & 7;
    const int q0 = qt * 128 + w * 32;

    // staging sources (pre-swizzled slots so swizzled reads see identity)
    const int rsub = lane >> 3;
    const int kslot = (lane & 7) ^ rsub;  // K rows: row&7 == lane>>3 for every issue
    const u16* gK = KV + (size_t)(b * NKV + w * 8 + rsub) * 1024 + h * DH + kslot * 8;
    const int vr7 = ((w & 1) << 2) | g;   // V rows: row&7
    const int vslot = (lane & 8) | ((lane & 7) ^ vr7);
    const u16* gV = Vt + (size_t)(bh * DH + w * 4 + g) * NKV + vslot * 8;

    bf16x8 qf[2][2];
#pragma unroll
    for (int itl = 0; itl < 2; ++itl) {
        const u16* qp = Q + (size_t)(b * NQ + q0 + itl * 16 + r) * DI + h * DH;
#pragma unroll
        for (int ks = 0; ks < 2; ++ks)
            qf[itl][ks] = *(const bf16x8*)(qp + ks * 32 + g * 8);
    }

    float mrow[2] = {-3e38f, -3e38f};
    float lrow[2] = {0.f, 0.f};
    f32x4 oacc[2][4];
#pragma unroll
    for (int a = 0; a < 2; ++a)
#pragma unroll
        for (int c = 0; c < 4; ++c) oacc[a][c] = {};

    const float c1 = 0.125f * 1.44269504f;  // scale * log2(e)

#pragma unroll 1
    for (int kv0 = 0; kv0 < NKV; kv0 += 128) {
        __syncthreads();  // previous tile's LDS reads complete
#pragma unroll
        for (int c = 0; c < 4; ++c) {
            gload16(gK + (size_t)(kv0 + c * 32) * 1024, (char*)lK + c * 4096 + w * 1024);
            gload16(gV + (size_t)(c * 16) * NKV + kv0, (char*)lV + c * 4096 + w * 1024);
        }
        __syncthreads();  // vmcnt drained by compiler before barrier

        // ---- QK^T (swapped): st = mfma(K, Q); lane(r,g) holds S[q=q0+16itl+r][j=16jt+4g+ii]
        f32x4 st[8][2];
        __builtin_amdgcn_s_setprio(1);
#pragma unroll
        for (int jt = 0; jt < 8; ++jt) {
            bf16x8 kf[2];
#pragma unroll
            for (int ks = 0; ks < 2; ++ks) {
                int row = jt * 16 + r;
                int byte = ((row << 7) | (ks << 6) | (g << 4)) ^ ((row & 7) << 4);
                kf[ks] = *(const bf16x8*)((const char*)lK + byte);
            }
#pragma unroll
            for (int itl = 0; itl < 2; ++itl) {
                f32x4 a = {};
                a = MFMA(kf[0], qf[itl][0], a);
                a = MFMA(kf[1], qf[itl][1], a);
                st[jt][itl] = a;
            }
        }
        __builtin_amdgcn_s_setprio(0);

        // ---- tile max (log2 domain) + defer-max rescale ----
        float pmax[2], corr[2] = {1.f, 1.f};
#pragma unroll
        for (int itl = 0; itl < 2; ++itl) {
            float mx = st[0][itl][0];
#pragma unroll
            for (int jt = 0; jt < 8; ++jt)
#pragma unroll
                for (int ii = 0; ii < 4; ++ii) mx = fmaxf(mx, st[jt][itl][ii]);
            mx = fmaxf(mx, __shfl_xor(mx, 16));
            mx = fmaxf(mx, __shfl_xor(mx, 32));
            pmax[itl] = mx * c1;
        }
        if (!__all(pmax[0] <= mrow[0] + 11.f && pmax[1] <= mrow[1] + 11.f)) {
#pragma unroll
            for (int itl = 0; itl < 2; ++itl) {
                float mnew = fmaxf(mrow[itl], pmax[itl]);
                corr[itl] = __builtin_amdgcn_exp2f(mrow[itl] - mnew);
                mrow[itl] = mnew;
            }
#pragma unroll
            for (int mtl = 0; mtl < 2; ++mtl)
#pragma unroll
                for (int ii = 0; ii < 4; ++ii) {
                    float c = __shfl(corr[mtl], g * 4 + ii);
#pragma unroll
                    for (int nt = 0; nt < 4; ++nt) oacc[mtl][nt][ii] *= c;
                }
        }

        // ---- exp + cvt_pk + permlane P-fragments, PV from lV ----
        float tsum[2] = {0.f, 0.f};
#pragma unroll
        for (int ks = 0; ks < 4; ++ks) {
            bf16x8 vf[4];
#pragma unroll
            for (int nt = 0; nt < 4; ++nt) {
                int row = nt * 16 + r;
                int byte = ((row << 8) | (ks << 6) | (g << 4)) ^ ((row & 7) << 4);
                vf[nt] = *(const bf16x8*)((const char*)lV + byte);
            }
            bf16x8 pa[2];
#pragma unroll
            for (int itl = 0; itl < 2; ++itl) {
                float e[8];
#pragma unroll
                for (int ii = 0; ii < 4; ++ii) {
                    e[ii]     = __builtin_amdgcn_exp2f(st[2 * ks][itl][ii] * c1 - mrow[itl]);
                    e[4 + ii] = __builtin_amdgcn_exp2f(st[2 * ks + 1][itl][ii] * c1 - mrow[itl]);
                }
#pragma unroll
                for (int ii = 0; ii < 8; ++ii) tsum[itl] += e[ii];
                u32 a0 = cvtpk(e[0], e[1]), a1 = cvtpk(e[2], e[3]);
                u32 b0 = cvtpk(e[4], e[5]), b1 = cvtpk(e[6], e[7]);
                asm("v_permlane32_swap_b32 %0, %1" : "+v"(a0), "+v"(b0));
                asm("v_permlane16_swap_b32 %0, %1" : "+v"(a0), "+v"(b0));
                asm("v_permlane32_swap_b32 %0, %1" : "+v"(a1), "+v"(b1));
                asm("v_permlane16_swap_b32 %0, %1" : "+v"(a1), "+v"(b1));
                union { u32 u[4]; bf16x8 v; } pk;
                pk.u[0] = a0; pk.u[1] = a1; pk.u[2] = b0; pk.u[3] = b1;
                pa[itl] = pk.v;
            }
            __builtin_amdgcn_s_setprio(1);
#pragma unroll
            for (int mtl = 0; mtl < 2; ++mtl)
#pragma unroll
                for (int nt = 0; nt < 4; ++nt)
                    oacc[mtl][nt] = MFMA(pa[mtl], vf[nt], oacc[mtl][nt]);
            __builtin_amdgcn_s_setprio(0);
        }
#pragma unroll
        for (int itl = 0; itl < 2; ++itl) {
            float s = tsum[itl];
            s += __shfl_xor(s, 16);
            s += __shfl_xor(s, 32);
            lrow[itl] = lrow[itl] * corr[itl] + s;
        }
    }

    // ---- normalize + store ----
#pragma unroll
    for (int mtl = 0; mtl < 2; ++mtl) {
#pragma unroll
        for (int ii = 0; ii < 4; ++ii) {
            float lv = __shfl(lrow[mtl], g * 4 + ii);
            float linv = __builtin_amdgcn_rcpf(lv);
            int i = q0 + mtl * 16 + g * 4 + ii;
#pragma unroll
            for (int nt = 0; nt < 4; ++nt) {
                int d = nt * 16 + r;
                O[(size_t)(b * NQ + i) * DI + h * DH + d] = f2bf(oacc[mtl][nt][ii] * linv);
            }
        }
    }
}

extern "C" void kernel_launch(void* const* d_in, const int* in_sizes, int n_in,
                              void* d_out, int out_size, void* d_ws, size_t ws_size,
                              hipStream_t stream) {
    (void)in_sizes; (void)n_in; (void)out_size; (void)ws_size;
    const float* x   = (const float*)d_in[0];
    const float* ctx = (const float*)d_in[1];
    const float* Wq  = (const float*)d_in[2];
    const float* Wk  = (const float*)d_in[3];
    const float* Wv  = (const float*)d_in[4];
    const float* Wo  = (const float*)d_in[5];
    const float* bo  = (const float*)d_in[6];
    float* out = (float*)d_out;

    char* ws = (char*)d_ws;
    u16* Wqt  = (u16*)(ws);                                  // 0.5 MB
    u16* Wkvt = (u16*)(ws + (size_t)524288);                 // 1.5 MB
    u16* Wot  = (u16*)(ws + (size_t)2097152);                // 0.5 MB
    u16* Qw   = (u16*)(ws + (size_t)2621440);                // 16 MB
    u16* KVw  = (u16*)(ws + (size_t)19398656);               // 8 MB
    u16* slotC = (u16*)(ws + (size_t)27787264);              // 16 MB: xb then Ow
    u16* slotD = (u16*)(ws + (size_t)44564480);              // 6 MB: ctxb then Vtw
    u16* xb   = slotC;
    u16* Ow   = slotC;
    u16* ctxb = slotD;
    u16* Vtw  = slotD;

    k_conv2<<<dim3(5632), 256, 0, stream>>>(x, xb, BB * NQ * QD / 8,
                                            ctx, ctxb, BB * NKV * CD / 8);
    k_transposeAll<<<dim3(24, 16, 4), 256, 0, stream>>>(Wq, Wk, Wv, Wo, Wqt, Wkvt, Wot);

    k_gemm<false, false><<<dim3(256, 4), 256, 0, stream>>>(xb, Wqt, Qw, nullptr, BB * NQ, DI, QD);
    k_gemm<false, false><<<dim3(64, 8), 256, 0, stream>>>(ctxb, Wkvt, KVw, nullptr, BB * NKV, 1024, CD);
    k_transposeV<<<dim3(32, 2, 32), 256, 0, stream>>>(KVw, Vtw);
    k_attn<<<dim3(32, 32), 256, 0, stream>>>(Qw, KVw, Vtw, Ow);
    k_gemm<true, true><<<dim3(256, 4), 256, 0, stream>>>(Ow, Wot, out, bo, BB * NQ, QD, DI);
}

// Round 5
// 194.818 us; speedup vs baseline: 1.4864x; 1.0433x over previous
//
#include <hip/hip_runtime.h>

typedef unsigned short u16;
typedef unsigned int u32;
typedef __bf16 bf16x8 __attribute__((ext_vector_type(8)));
typedef float f32x4 __attribute__((ext_vector_type(4)));
typedef u16 u16x8 __attribute__((ext_vector_type(8)));

#define BB 4
#define NQ 4096
#define NKV 1024
#define QD 512
#define CD 768
#define NH 8
#define DH 64
#define DI 512

__device__ __forceinline__ u16 f2bf(float f) {
    u32 u = __float_as_uint(f);
    u = (u + 0x7fffu + ((u >> 16) & 1u)) >> 16;
    return (u16)u;
}

__device__ __forceinline__ u32 cvtpk(float lo, float hi) {
    u32 r;
    asm("v_cvt_pk_bf16_f32 %0, %1, %2" : "=v"(r) : "v"(lo), "v"(hi));
    return r;
}

__device__ __forceinline__ void gload16(const void* g, void* l) {
    __builtin_amdgcn_global_load_lds(
        (const __attribute__((address_space(1))) u32*)g,
        (__attribute__((address_space(3))) u32*)l, 16, 0, 0);
}

__device__ __forceinline__ f32x4 MFMA(bf16x8 a, bf16x8 b, f32x4 c) {
    return __builtin_amdgcn_mfma_f32_16x16x32_bf16(a, b, c, 0, 0, 0);
}

__device__ __forceinline__ bf16x8 ones8() {
    union { u16 u[8]; bf16x8 v; } o;
#pragma unroll
    for (int i = 0; i < 8; ++i) o.u[i] = 0x3F80;  // bf16 1.0
    return o.v;
}

// ---------- prep: f32->bf16 for x & ctx, + all 4 weight transposes, one launch ----------
// blocks: [0,4096) conv-x, [4096,5632) conv-ctx, [5632,6912) transposes
__global__ __launch_bounds__(256)
void k_prep(const float* __restrict__ x, u16* __restrict__ xb,
            const float* __restrict__ ctx, u16* __restrict__ ctxb,
            const float* __restrict__ Wq, const float* __restrict__ Wk,
            const float* __restrict__ Wv, const float* __restrict__ Wo,
            u16* __restrict__ Wqt, u16* __restrict__ Wkvt, u16* __restrict__ Wot) {
    __shared__ float tile[32][33];
    int bid = blockIdx.x;
    if (bid < 5632) {
        const float* in; u16* out; int j;
        int i = bid * 256 + threadIdx.x;
        if (i < 4096 * 256) { in = x; out = xb; j = i; }
        else { j = i - 4096 * 256; in = ctx; out = ctxb; }
        float4 u0 = ((const float4*)in)[2 * j];
        float4 u1 = ((const float4*)in)[2 * j + 1];
        uint4 v;
        v.x = cvtpk(u0.x, u0.y);
        v.y = cvtpk(u0.z, u0.w);
        v.z = cvtpk(u1.x, u1.y);
        v.w = cvtpk(u1.z, u1.w);
        ((uint4*)out)[j] = v;
        return;
    }
    int tb = bid - 5632;
    const float* W; u16* Wt; int K, nblk;
    if (tb < 256)      { W = Wq; Wt = Wqt;                      K = 512; nblk = tb; }
    else if (tb < 640) { W = Wk; Wt = Wkvt;                     K = 768; nblk = tb - 256; }
    else if (tb < 1024){ W = Wv; Wt = Wkvt + (size_t)512 * 768; K = 768; nblk = tb - 640; }
    else               { W = Wo; Wt = Wot;                      K = 512; nblk = tb - 1024; }
    int kb = (nblk >> 4) * 32, nb = (nblk & 15) * 32;
    int tx = threadIdx.x & 31, ty = threadIdx.x >> 5;
    for (int i = ty; i < 32; i += 8)
        tile[i][tx] = W[(size_t)(kb + i) * 512 + nb + tx];
    __syncthreads();
    for (int i = ty; i < 32; i += 8)
        Wt[(size_t)(nb + i) * K + kb + tx] = f2bf(tile[tx][i]);
}

// ---------- V transpose: Vt[(bh*64+d)*NKV + j] = KV[(b*NKV+j)*1024 + 512 + h*64 + d] ----------
__global__ __launch_bounds__(256)
void k_transposeV(const u16* __restrict__ KV, u16* __restrict__ Vt) {
    __shared__ u16 tile[32][33];
    int j0 = blockIdx.x * 32, d0 = blockIdx.y * 32, bh = blockIdx.z;
    int b = bh >> 3, h = bh & 7;
    int tx = threadIdx.x & 31, ty = threadIdx.x >> 5;
    for (int i = ty; i < 32; i += 8)
        tile[i][tx] = KV[(size_t)(b * NKV + j0 + i) * 1024 + 512 + h * DH + d0 + tx];
    __syncthreads();
    for (int i = ty; i < 32; i += 8)
        Vt[(size_t)(bh * DH + d0 + i) * NKV + j0 + tx] = tile[tx][i];
}

// ---------- GEMM body: C[.][N] (+bias) = A[.][K] @ Bt[N][K]^T, BM=BN=128 BK=64,
// double-buffered gload_lds, single barrier per K-step ----------
template <bool OUTF32, bool BIAS>
__device__ __forceinline__ void gemm_body(const u16* __restrict__ A, const u16* __restrict__ Bt,
                                          void* __restrict__ Cv, const float* __restrict__ bias,
                                          int N, int K, int m0, int n0) {
    __shared__ u16 lA[2][128 * 64];
    __shared__ u16 lB[2][128 * 64];
    const int t = threadIdx.x;
    const int w = t >> 6, lane = t & 63, r = lane & 15, g = lane >> 4;
    const int wm = (w >> 1) * 64, wn = (w & 1) * 64;
    const int rsub = lane >> 3;
    const int slot = (lane & 7) ^ rsub;
    const u16* gA = A + (size_t)(m0 + w * 8 + rsub) * K + slot * 8;
    const u16* gB = Bt + (size_t)(n0 + w * 8 + rsub) * K + slot * 8;

    f32x4 acc[4][4];
#pragma unroll
    for (int a = 0; a < 4; ++a)
#pragma unroll
        for (int c = 0; c < 4; ++c) acc[a][c] = {};

    auto STAGE = [&](int kt, int bufi) {
#pragma unroll
        for (int c = 0; c < 4; ++c) {
            gload16(gA + (size_t)(c * 32) * K + kt, (char*)lA[bufi] + c * 4096 + w * 1024);
            gload16(gB + (size_t)(c * 32) * K + kt, (char*)lB[bufi] + c * 4096 + w * 1024);
        }
    };
    auto COMP = [&](int bufi) {
        __builtin_amdgcn_s_setprio(1);
#pragma unroll
        for (int ks = 0; ks < 2; ++ks) {
            bf16x8 af[4], bfr[4];
#pragma unroll
            for (int mt = 0; mt < 4; ++mt) {
                int row = wm + mt * 16 + r;
                int byte = ((row << 7) | (ks << 6) | (g << 4)) ^ ((row & 7) << 4);
                af[mt] = *(const bf16x8*)((const char*)lA[bufi] + byte);
            }
#pragma unroll
            for (int nt = 0; nt < 4; ++nt) {
                int row = wn + nt * 16 + r;
                int byte = ((row << 7) | (ks << 6) | (g << 4)) ^ ((row & 7) << 4);
                bfr[nt] = *(const bf16x8*)((const char*)lB[bufi] + byte);
            }
#pragma unroll
            for (int mt = 0; mt < 4; ++mt)
#pragma unroll
                for (int nt = 0; nt < 4; ++nt)
                    acc[mt][nt] = MFMA(af[mt], bfr[nt], acc[mt][nt]);
        }
        __builtin_amdgcn_s_setprio(0);
    };

    STAGE(0, 0);
    __syncthreads();
#pragma unroll 1
    for (int kt = 0; kt < K; kt += 128) {
        if (kt + 64 < K) STAGE(kt + 64, 1);
        COMP(0);
        __syncthreads();
        if (kt + 128 < K) STAGE(kt + 128, 0);
        if (kt + 64 < K) {
            COMP(1);
            __syncthreads();
        }
    }
#pragma unroll
    for (int mt = 0; mt < 4; ++mt) {
#pragma unroll
        for (int i = 0; i < 4; ++i) {
            int row = m0 + wm + mt * 16 + g * 4 + i;
#pragma unroll
            for (int nt = 0; nt < 4; ++nt) {
                int col = n0 + wn + nt * 16 + r;
                float vv = acc[mt][nt][i];
                if constexpr (BIAS) vv += bias[col];
                if constexpr (OUTF32) ((float*)Cv)[(size_t)row * N + col] = vv;
                else ((u16*)Cv)[(size_t)row * N + col] = f2bf(vv);
            }
        }
    }
}

// fused Q-proj + KV-proj: blocks [0,512) Qproj (128x4), [512,768) KVproj (32x8)
__global__ __launch_bounds__(256, 2)
void k_gemm_qkv(const u16* __restrict__ xb, const u16* __restrict__ Wqt, u16* __restrict__ Qw,
                const u16* __restrict__ ctxb, const u16* __restrict__ Wkvt, u16* __restrict__ KVw) {
    int bid = blockIdx.x;
    if (bid < 512)
        gemm_body<false, false>(xb, Wqt, Qw, nullptr, 512, 512, (bid >> 2) * 128, (bid & 3) * 128);
    else {
        bid -= 512;
        gemm_body<false, false>(ctxb, Wkvt, KVw, nullptr, 1024, 768, (bid >> 3) * 128, (bid & 7) * 128);
    }
}

__global__ __launch_bounds__(256, 2)
void k_gemm_o(const u16* __restrict__ Ow, const u16* __restrict__ Wot,
              float* __restrict__ out, const float* __restrict__ bo) {
    int bid = blockIdx.x;
    gemm_body<true, true>(Ow, Wot, out, bo, 512, 512, (bid >> 2) * 128, (bid & 3) * 128);
}

// ---------- flash attention: dbuf K/V LDS, pipelined single barrier, P in-register,
// row-sum via MFMA-with-ones ----------
__global__ __launch_bounds__(256, 2)
void k_attn(const u16* __restrict__ Q, const u16* __restrict__ KV,
            const u16* __restrict__ Vt, u16* __restrict__ O) {
    __shared__ u16 lK[2][128 * 64];  // [j][d], 128B rows, XOR swizzle ((row&7)<<4)
    __shared__ u16 lV[2][64 * 128];  // [d][j], 256B rows, XOR swizzle ((row&7)<<4)
    const int t = threadIdx.x;
    const int w = t >> 6, lane = t & 63, r = lane & 15, g = lane >> 4;
    const int bh = blockIdx.x, qt = blockIdx.y;  // bh fastest => KV L2-local per XCD
    const int b = bh >> 3, h = bh & 7;
    const int q0 = qt * 128 + w * 32;

    const int rsub = lane >> 3;
    const int kslot = (lane & 7) ^ rsub;
    const u16* gK = KV + (size_t)(b * NKV + w * 8 + rsub) * 1024 + h * DH + kslot * 8;
    const int vr7 = ((w & 1) << 2) | g;
    const int vslot = (lane & 8) | ((lane & 7) ^ vr7);
    const u16* gV = Vt + (size_t)(bh * DH + w * 4 + g) * NKV + vslot * 8;

    bf16x8 qf[2][2];
#pragma unroll
    for (int itl = 0; itl < 2; ++itl) {
        const u16* qp = Q + (size_t)(b * NQ + q0 + itl * 16 + r) * DI + h * DH;
#pragma unroll
        for (int ks = 0; ks < 2; ++ks)
            qf[itl][ks] = *(const bf16x8*)(qp + ks * 32 + g * 8);
    }

    const bf16x8 vOnes = ones8();
    float mrow[2] = {-3e38f, -3e38f};
    f32x4 oacc[2][4], lacc[2];
#pragma unroll
    for (int a = 0; a < 2; ++a) {
        lacc[a] = {};
#pragma unroll
        for (int c = 0; c < 4; ++c) oacc[a][c] = {};
    }

    const float c1 = 0.125f * 1.44269504f;  // scale * log2(e)

    auto STAGE = [&](int kv0, int bufi) {
#pragma unroll
        for (int c = 0; c < 4; ++c) {
            gload16(gK + (size_t)(kv0 + c * 32) * 1024, (char*)lK[bufi] + c * 4096 + w * 1024);
            gload16(gV + (size_t)(c * 16) * NKV + kv0, (char*)lV[bufi] + c * 4096 + w * 1024);
        }
    };

    auto TILE = [&](int bufi) {
        // QK^T (swapped): lane(r,g) holds S[q=q0+16itl+r][j=16jt+4g+ii]
        f32x4 st[8][2];
        __builtin_amdgcn_s_setprio(1);
#pragma unroll
        for (int jt = 0; jt < 8; ++jt) {
            bf16x8 kf[2];
#pragma unroll
            for (int ks = 0; ks < 2; ++ks) {
                int row = jt * 16 + r;
                int byte = ((row << 7) | (ks << 6) | (g << 4)) ^ ((row & 7) << 4);
                kf[ks] = *(const bf16x8*)((const char*)lK[bufi] + byte);
            }
#pragma unroll
            for (int itl = 0; itl < 2; ++itl) {
                f32x4 a = {};
                a = MFMA(kf[0], qf[itl][0], a);
                a = MFMA(kf[1], qf[itl][1], a);
                st[jt][itl] = a;
            }
        }
        __builtin_amdgcn_s_setprio(0);

        // tile max (log2 domain) + defer-max rescale (l rescales with O)
        float pmax[2];
#pragma unroll
        for (int itl = 0; itl < 2; ++itl) {
            float mx = st[0][itl][0];
#pragma unroll
            for (int jt = 0; jt < 8; ++jt)
#pragma unroll
                for (int ii = 0; ii < 4; ++ii) mx = fmaxf(mx, st[jt][itl][ii]);
            mx = fmaxf(mx, __shfl_xor(mx, 16));
            mx = fmaxf(mx, __shfl_xor(mx, 32));
            pmax[itl] = mx * c1;
        }
        if (!__all(pmax[0] <= mrow[0] + 11.f && pmax[1] <= mrow[1] + 11.f)) {
            float corr[2];
#pragma unroll
            for (int itl = 0; itl < 2; ++itl) {
                float mnew = fmaxf(mrow[itl], pmax[itl]);
                corr[itl] = __builtin_amdgcn_exp2f(mrow[itl] - mnew);
                mrow[itl] = mnew;
            }
#pragma unroll
            for (int mtl = 0; mtl < 2; ++mtl)
#pragma unroll
                for (int ii = 0; ii < 4; ++ii) {
                    float c = __shfl(corr[mtl], g * 4 + ii);
#pragma unroll
                    for (int nt = 0; nt < 4; ++nt) oacc[mtl][nt][ii] *= c;
                    lacc[mtl][ii] *= c;
                }
        }

        // exp + cvt_pk + permlane P-fragments, PV (+ rowsum via ones)
#pragma unroll
        for (int ks = 0; ks < 4; ++ks) {
            bf16x8 vf[4];
#pragma unroll
            for (int nt = 0; nt < 4; ++nt) {
                int row = nt * 16 + r;
                int byte = ((row << 8) | (ks << 6) | (g << 4)) ^ ((row & 7) << 4);
                vf[nt] = *(const bf16x8*)((const char*)lV[bufi] + byte);
            }
            bf16x8 pa[2];
#pragma unroll
            for (int itl = 0; itl < 2; ++itl) {
                float e[8];
#pragma unroll
                for (int ii = 0; ii < 4; ++ii) {
                    e[ii]     = __builtin_amdgcn_exp2f(st[2 * ks][itl][ii] * c1 - mrow[itl]);
                    e[4 + ii] = __builtin_amdgcn_exp2f(st[2 * ks + 1][itl][ii] * c1 - mrow[itl]);
                }
                u32 a0 = cvtpk(e[0], e[1]), a1 = cvtpk(e[2], e[3]);
                u32 b0 = cvtpk(e[4], e[5]), b1 = cvtpk(e[6], e[7]);
                asm("v_permlane32_swap_b32 %0, %1" : "+v"(a0), "+v"(b0));
                asm("v_permlane16_swap_b32 %0, %1" : "+v"(a0), "+v"(b0));
                asm("v_permlane32_swap_b32 %0, %1" : "+v"(a1), "+v"(b1));
                asm("v_permlane16_swap_b32 %0, %1" : "+v"(a1), "+v"(b1));
                union { u32 u[4]; bf16x8 v; } pk;
                pk.u[0] = a0; pk.u[1] = a1; pk.u[2] = b0; pk.u[3] = b1;
                pa[itl] = pk.v;
            }
            __builtin_amdgcn_s_setprio(1);
#pragma unroll
            for (int mtl = 0; mtl < 2; ++mtl) {
#pragma unroll
                for (int nt = 0; nt < 4; ++nt)
                    oacc[mtl][nt] = MFMA(pa[mtl], vf[nt], oacc[mtl][nt]);
                lacc[mtl] = MFMA(pa[mtl], vOnes, lacc[mtl]);
            }
            __builtin_amdgcn_s_setprio(0);
        }
    };

    STAGE(0, 0);
    __syncthreads();
#pragma unroll 1
    for (int kv0 = 0; kv0 < NKV; kv0 += 256) {
        STAGE(kv0 + 128, 1);
        TILE(0);
        __syncthreads();
        if (kv0 + 256 < NKV) STAGE(kv0 + 256, 0);
        TILE(1);
        __syncthreads();
    }

    // normalize + store (lacc aligned with oacc: no shuffles)
#pragma unroll
    for (int mtl = 0; mtl < 2; ++mtl) {
#pragma unroll
        for (int ii = 0; ii < 4; ++ii) {
            float linv = __builtin_amdgcn_rcpf(lacc[mtl][ii]);
            int i = q0 + mtl * 16 + g * 4 + ii;
#pragma unroll
            for (int nt = 0; nt < 4; ++nt) {
                int d = nt * 16 + r;
                O[(size_t)(b * NQ + i) * DI + h * DH + d] = f2bf(oacc[mtl][nt][ii] * linv);
            }
        }
    }
}

extern "C" void kernel_launch(void* const* d_in, const int* in_sizes, int n_in,
                              void* d_out, int out_size, void* d_ws, size_t ws_size,
                              hipStream_t stream) {
    (void)in_sizes; (void)n_in; (void)out_size; (void)ws_size;
    const float* x   = (const float*)d_in[0];
    const float* ctx = (const float*)d_in[1];
    const float* Wq  = (const float*)d_in[2];
    const float* Wk  = (const float*)d_in[3];
    const float* Wv  = (const float*)d_in[4];
    const float* Wo  = (const float*)d_in[5];
    const float* bo  = (const float*)d_in[6];
    float* out = (float*)d_out;

    char* ws = (char*)d_ws;
    u16* Wqt  = (u16*)(ws);                                  // 0.5 MB
    u16* Wkvt = (u16*)(ws + (size_t)524288);                 // 1.5 MB
    u16* Wot  = (u16*)(ws + (size_t)2097152);                // 0.5 MB
    u16* Qw   = (u16*)(ws + (size_t)2621440);                // 16 MB
    u16* KVw  = (u16*)(ws + (size_t)19398656);               // 8 MB
    u16* slotC = (u16*)(ws + (size_t)27787264);              // 16 MB: xb then Ow
    u16* slotD = (u16*)(ws + (size_t)44564480);              // 6 MB: ctxb then Vtw
    u16* xb   = slotC;
    u16* Ow   = slotC;
    u16* ctxb = slotD;
    u16* Vtw  = slotD;

    k_prep<<<dim3(6912), 256, 0, stream>>>(x, xb, ctx, ctxb, Wq, Wk, Wv, Wo, Wqt, Wkvt, Wot);
    k_gemm_qkv<<<dim3(768), 256, 0, stream>>>(xb, Wqt, Qw, ctxb, Wkvt, KVw);
    k_transposeV<<<dim3(32, 2, 32), 256, 0, stream>>>(KVw, Vtw);
    k_attn<<<dim3(32, 32), 256, 0, stream>>>(Qw, KVw, Vtw, Ow);
    k_gemm_o<<<dim3(512), 256, 0, stream>>>(Ow, Wot, out, bo);
}

// Round 7
// 192.366 us; speedup vs baseline: 1.5054x; 1.0127x over previous
//
#include <hip/hip_runtime.h>

typedef unsigned short u16;
typedef unsigned int u32;
typedef __bf16 bf16x8 __attribute__((ext_vector_type(8)));
typedef float f32x4 __attribute__((ext_vector_type(4)));
typedef u16 u16x8 __attribute__((ext_vector_type(8)));

#define BB 4
#define NQ 4096
#define NKV 1024
#define QD 512
#define CD 768
#define NH 8
#define DH 64
#define DI 512

__device__ __forceinline__ u16 f2bf(float f) {
    u32 u = __float_as_uint(f);
    u = (u + 0x7fffu + ((u >> 16) & 1u)) >> 16;
    return (u16)u;
}

__device__ __forceinline__ u32 cvtpk(float lo, float hi) {
    u32 r;
    asm("v_cvt_pk_bf16_f32 %0, %1, %2" : "=v"(r) : "v"(lo), "v"(hi));
    return r;
}

__device__ __forceinline__ void gload16(const void* g, void* l) {
    __builtin_amdgcn_global_load_lds(
        (const __attribute__((address_space(1))) u32*)g,
        (__attribute__((address_space(3))) u32*)l, 16, 0, 0);
}

__device__ __forceinline__ f32x4 MFMA(bf16x8 a, bf16x8 b, f32x4 c) {
    return __builtin_amdgcn_mfma_f32_16x16x32_bf16(a, b, c, 0, 0, 0);
}

__device__ __forceinline__ bf16x8 ones8() {
    union { u16 u[8]; bf16x8 v; } o;
#pragma unroll
    for (int i = 0; i < 8; ++i) o.u[i] = 0x3F80;  // bf16 1.0
    return o.v;
}

// ---------- prep: f32->bf16 for x & ctx, + all 4 weight transposes, one launch ----------
__global__ __launch_bounds__(256)
void k_prep(const float* __restrict__ x, u16* __restrict__ xb,
            const float* __restrict__ ctx, u16* __restrict__ ctxb,
            const float* __restrict__ Wq, const float* __restrict__ Wk,
            const float* __restrict__ Wv, const float* __restrict__ Wo,
            u16* __restrict__ Wqt, u16* __restrict__ Wkvt, u16* __restrict__ Wot) {
    __shared__ float tile[32][33];
    int bid = blockIdx.x;
    if (bid < 5632) {
        const float* in; u16* out; int j;
        int i = bid * 256 + threadIdx.x;
        if (i < 4096 * 256) { in = x; out = xb; j = i; }
        else { j = i - 4096 * 256; in = ctx; out = ctxb; }
        float4 u0 = ((const float4*)in)[2 * j];
        float4 u1 = ((const float4*)in)[2 * j + 1];
        uint4 v;
        v.x = cvtpk(u0.x, u0.y);
        v.y = cvtpk(u0.z, u0.w);
        v.z = cvtpk(u1.x, u1.y);
        v.w = cvtpk(u1.z, u1.w);
        ((uint4*)out)[j] = v;
        return;
    }
    int tb = bid - 5632;
    const float* W; u16* Wt; int K, nblk;
    if (tb < 256)      { W = Wq; Wt = Wqt;                      K = 512; nblk = tb; }
    else if (tb < 640) { W = Wk; Wt = Wkvt;                     K = 768; nblk = tb - 256; }
    else if (tb < 1024){ W = Wv; Wt = Wkvt + (size_t)512 * 768; K = 768; nblk = tb - 640; }
    else               { W = Wo; Wt = Wot;                      K = 512; nblk = tb - 1024; }
    int kb = (nblk >> 4) * 32, nb = (nblk & 15) * 32;
    int tx = threadIdx.x & 31, ty = threadIdx.x >> 5;
    for (int i = ty; i < 32; i += 8)
        tile[i][tx] = W[(size_t)(kb + i) * 512 + nb + tx];
    __syncthreads();
    for (int i = ty; i < 32; i += 8)
        Wt[(size_t)(nb + i) * K + kb + tx] = f2bf(tile[tx][i]);
}

// ---------- V transpose: Vt[(bh*64+d)*NKV + j] = KV[(b*NKV+j)*1024 + 512 + h*64 + d] ----------
__global__ __launch_bounds__(256)
void k_transposeV(const u16* __restrict__ KV, u16* __restrict__ Vt) {
    __shared__ u16 tile[32][33];
    int j0 = blockIdx.x * 32, d0 = blockIdx.y * 32, bh = blockIdx.z;
    int b = bh >> 3, h = bh & 7;
    int tx = threadIdx.x & 31, ty = threadIdx.x >> 5;
    for (int i = ty; i < 32; i += 8)
        tile[i][tx] = KV[(size_t)(b * NKV + j0 + i) * 1024 + 512 + h * DH + d0 + tx];
    __syncthreads();
    for (int i = ty; i < 32; i += 8)
        Vt[(size_t)(bh * DH + d0 + i) * NKV + j0 + tx] = tile[tx][i];
}

// ---------- GEMM body (m97 structure): C = A @ Bt^T (+bias), BM=BN=128 BK=64,
// SINGLE 32KB LDS buffer (hoisted, passed in), stage -> barrier -> compute -> barrier ----------
template <bool OUTF32, bool BIAS>
__device__ __forceinline__ void gemm_body(const u16* __restrict__ A, const u16* __restrict__ Bt,
                                          void* __restrict__ Cv, const float* __restrict__ bias,
                                          int N, int K, int m0, int n0,
                                          u16* lA, u16* lB) {
    const int t = threadIdx.x;
    const int w = t >> 6, lane = t & 63, r = lane & 15, g = lane >> 4;
    const int wm = (w >> 1) * 64, wn = (w & 1) * 64;
    const int rsub = lane >> 3;
    const int slot = (lane & 7) ^ rsub;
    const u16* gA = A + (size_t)(m0 + w * 8 + rsub) * K + slot * 8;
    const u16* gB = Bt + (size_t)(n0 + w * 8 + rsub) * K + slot * 8;

    f32x4 acc[4][4];
#pragma unroll
    for (int a = 0; a < 4; ++a)
#pragma unroll
        for (int c = 0; c < 4; ++c) acc[a][c] = {};

#pragma unroll 1
    for (int kt = 0; kt < K; kt += 64) {
        __syncthreads();  // LDS free to overwrite
#pragma unroll
        for (int c = 0; c < 4; ++c) {
            gload16(gA + (size_t)(c * 32) * K + kt, (char*)lA + c * 4096 + w * 1024);
            gload16(gB + (size_t)(c * 32) * K + kt, (char*)lB + c * 4096 + w * 1024);
        }
        __syncthreads();  // loads drained (compiler vmcnt(0) before barrier)
        __builtin_amdgcn_s_setprio(1);
#pragma unroll
        for (int ks = 0; ks < 2; ++ks) {
            bf16x8 af[4], bfr[4];
#pragma unroll
            for (int mt = 0; mt < 4; ++mt) {
                int row = wm + mt * 16 + r;
                int byte = ((row << 7) | (ks << 6) | (g << 4)) ^ ((row & 7) << 4);
                af[mt] = *(const bf16x8*)((const char*)lA + byte);
            }
#pragma unroll
            for (int nt = 0; nt < 4; ++nt) {
                int row = wn + nt * 16 + r;
                int byte = ((row << 7) | (ks << 6) | (g << 4)) ^ ((row & 7) << 4);
                bfr[nt] = *(const bf16x8*)((const char*)lB + byte);
            }
#pragma unroll
            for (int mt = 0; mt < 4; ++mt)
#pragma unroll
                for (int nt = 0; nt < 4; ++nt)
                    acc[mt][nt] = MFMA(af[mt], bfr[nt], acc[mt][nt]);
        }
        __builtin_amdgcn_s_setprio(0);
    }
#pragma unroll
    for (int mt = 0; mt < 4; ++mt) {
#pragma unroll
        for (int i = 0; i < 4; ++i) {
            int row = m0 + wm + mt * 16 + g * 4 + i;
#pragma unroll
            for (int nt = 0; nt < 4; ++nt) {
                int col = n0 + wn + nt * 16 + r;
                float vv = acc[mt][nt][i];
                if constexpr (BIAS) vv += bias[col];
                if constexpr (OUTF32) ((float*)Cv)[(size_t)row * N + col] = vv;
                else ((u16*)Cv)[(size_t)row * N + col] = f2bf(vv);
            }
        }
    }
}

// fused Q-proj + KV-proj: blocks [0,512) Qproj (128x4), [512,768) KVproj (32x8)
// ONE shared buffer at kernel scope, shared by both branches
__global__ __launch_bounds__(256, 3)
void k_gemm_qkv(const u16* __restrict__ xb, const u16* __restrict__ Wqt, u16* __restrict__ Qw,
                const u16* __restrict__ ctxb, const u16* __restrict__ Wkvt, u16* __restrict__ KVw) {
    __shared__ u16 sm[2][128 * 64];
    int bid = blockIdx.x;
    if (bid < 512)
        gemm_body<false, false>(xb, Wqt, Qw, nullptr, 512, 512,
                                (bid >> 2) * 128, (bid & 3) * 128, sm[0], sm[1]);
    else {
        bid -= 512;
        gemm_body<false, false>(ctxb, Wkvt, KVw, nullptr, 1024, 768,
                                (bid >> 3) * 128, (bid & 7) * 128, sm[0], sm[1]);
    }
}

__global__ __launch_bounds__(256, 3)
void k_gemm_o(const u16* __restrict__ Ow, const u16* __restrict__ Wot,
              float* __restrict__ out, const float* __restrict__ bo) {
    __shared__ u16 sm[2][128 * 64];
    int bid = blockIdx.x;
    gemm_body<true, true>(Ow, Wot, out, bo, 512, 512,
                          (bid >> 2) * 128, (bid & 3) * 128, sm[0], sm[1]);
}

// ---------- flash attention (VERBATIM from round-5 PASS): KVBLK=128, dbuf K/V LDS,
// pipelined single barrier, P in-register, row-sum via MFMA-with-ones ----------
__global__ __launch_bounds__(256, 2)
void k_attn(const u16* __restrict__ Q, const u16* __restrict__ KV,
            const u16* __restrict__ Vt, u16* __restrict__ O) {
    __shared__ u16 lK[2][128 * 64];  // [j][d], 128B rows, XOR swizzle ((row&7)<<4)
    __shared__ u16 lV[2][64 * 128];  // [d][j], 256B rows, XOR swizzle ((row&7)<<4)
    const int t = threadIdx.x;
    const int w = t >> 6, lane = t & 63, r = lane & 15, g = lane >> 4;
    const int bh = blockIdx.x, qt = blockIdx.y;  // bh fastest => KV L2-local per XCD
    const int b = bh >> 3, h = bh & 7;
    const int q0 = qt * 128 + w * 32;

    const int rsub = lane >> 3;
    const int kslot = (lane & 7) ^ rsub;
    const u16* gK = KV + (size_t)(b * NKV + w * 8 + rsub) * 1024 + h * DH + kslot * 8;
    const int vr7 = ((w & 1) << 2) | g;
    const int vslot = (lane & 8) | ((lane & 7) ^ vr7);
    const u16* gV = Vt + (size_t)(bh * DH + w * 4 + g) * NKV + vslot * 8;

    bf16x8 qf[2][2];
#pragma unroll
    for (int itl = 0; itl < 2; ++itl) {
        const u16* qp = Q + (size_t)(b * NQ + q0 + itl * 16 + r) * DI + h * DH;
#pragma unroll
        for (int ks = 0; ks < 2; ++ks)
            qf[itl][ks] = *(const bf16x8*)(qp + ks * 32 + g * 8);
    }

    const bf16x8 vOnes = ones8();
    float mrow[2] = {-3e38f, -3e38f};
    f32x4 oacc[2][4], lacc[2];
#pragma unroll
    for (int a = 0; a < 2; ++a) {
        lacc[a] = {};
#pragma unroll
        for (int c = 0; c < 4; ++c) oacc[a][c] = {};
    }

    const float c1 = 0.125f * 1.44269504f;  // scale * log2(e)

    auto STAGE = [&](int kv0, int bufi) {
#pragma unroll
        for (int c = 0; c < 4; ++c) {
            gload16(gK + (size_t)(kv0 + c * 32) * 1024, (char*)lK[bufi] + c * 4096 + w * 1024);
            gload16(gV + (size_t)(c * 16) * NKV + kv0, (char*)lV[bufi] + c * 4096 + w * 1024);
        }
    };

    auto TILE = [&](int bufi) {
        // QK^T (swapped): lane(r,g) holds S[q=q0+16itl+r][j=16jt+4g+ii]
        f32x4 st[8][2];
        __builtin_amdgcn_s_setprio(1);
#pragma unroll
        for (int jt = 0; jt < 8; ++jt) {
            bf16x8 kf[2];
#pragma unroll
            for (int ks = 0; ks < 2; ++ks) {
                int row = jt * 16 + r;
                int byte = ((row << 7) | (ks << 6) | (g << 4)) ^ ((row & 7) << 4);
                kf[ks] = *(const bf16x8*)((const char*)lK[bufi] + byte);
            }
#pragma unroll
            for (int itl = 0; itl < 2; ++itl) {
                f32x4 a = {};
                a = MFMA(kf[0], qf[itl][0], a);
                a = MFMA(kf[1], qf[itl][1], a);
                st[jt][itl] = a;
            }
        }
        __builtin_amdgcn_s_setprio(0);

        // tile max (log2 domain) + defer-max rescale (l rescales with O)
        float pmax[2];
#pragma unroll
        for (int itl = 0; itl < 2; ++itl) {
            float mx = st[0][itl][0];
#pragma unroll
            for (int jt = 0; jt < 8; ++jt)
#pragma unroll
                for (int ii = 0; ii < 4; ++ii) mx = fmaxf(mx, st[jt][itl][ii]);
            mx = fmaxf(mx, __shfl_xor(mx, 16));
            mx = fmaxf(mx, __shfl_xor(mx, 32));
            pmax[itl] = mx * c1;
        }
        if (!__all(pmax[0] <= mrow[0] + 11.f && pmax[1] <= mrow[1] + 11.f)) {
            float corr[2];
#pragma unroll
            for (int itl = 0; itl < 2; ++itl) {
                float mnew = fmaxf(mrow[itl], pmax[itl]);
                corr[itl] = __builtin_amdgcn_exp2f(mrow[itl] - mnew);
                mrow[itl] = mnew;
            }
#pragma unroll
            for (int mtl = 0; mtl < 2; ++mtl)
#pragma unroll
                for (int ii = 0; ii < 4; ++ii) {
                    float c = __shfl(corr[mtl], g * 4 + ii);
#pragma unroll
                    for (int nt = 0; nt < 4; ++nt) oacc[mtl][nt][ii] *= c;
                    lacc[mtl][ii] *= c;
                }
        }

        // exp + cvt_pk + permlane P-fragments, PV (+ rowsum via ones)
#pragma unroll
        for (int ks = 0; ks < 4; ++ks) {
            bf16x8 vf[4];
#pragma unroll
            for (int nt = 0; nt < 4; ++nt) {
                int row = nt * 16 + r;
                int byte = ((row << 8) | (ks << 6) | (g << 4)) ^ ((row & 7) << 4);
                vf[nt] = *(const bf16x8*)((const char*)lV[bufi] + byte);
            }
            bf16x8 pa[2];
#pragma unroll
            for (int itl = 0; itl < 2; ++itl) {
                float e[8];
#pragma unroll
                for (int ii = 0; ii < 4; ++ii) {
                    e[ii]     = __builtin_amdgcn_exp2f(st[2 * ks][itl][ii] * c1 - mrow[itl]);
                    e[4 + ii] = __builtin_amdgcn_exp2f(st[2 * ks + 1][itl][ii] * c1 - mrow[itl]);
                }
                u32 a0 = cvtpk(e[0], e[1]), a1 = cvtpk(e[2], e[3]);
                u32 b0 = cvtpk(e[4], e[5]), b1 = cvtpk(e[6], e[7]);
                asm("v_permlane32_swap_b32 %0, %1" : "+v"(a0), "+v"(b0));
                asm("v_permlane16_swap_b32 %0, %1" : "+v"(a0), "+v"(b0));
                asm("v_permlane32_swap_b32 %0, %1" : "+v"(a1), "+v"(b1));
                asm("v_permlane16_swap_b32 %0, %1" : "+v"(a1), "+v"(b1));
                union { u32 u[4]; bf16x8 v; } pk;
                pk.u[0] = a0; pk.u[1] = a1; pk.u[2] = b0; pk.u[3] = b1;
                pa[itl] = pk.v;
            }
            __builtin_amdgcn_s_setprio(1);
#pragma unroll
            for (int mtl = 0; mtl < 2; ++mtl) {
#pragma unroll
                for (int nt = 0; nt < 4; ++nt)
                    oacc[mtl][nt] = MFMA(pa[mtl], vf[nt], oacc[mtl][nt]);
                lacc[mtl] = MFMA(pa[mtl], vOnes, lacc[mtl]);
            }
            __builtin_amdgcn_s_setprio(0);
        }
    };

    STAGE(0, 0);
    __syncthreads();
#pragma unroll 1
    for (int kv0 = 0; kv0 < NKV; kv0 += 256) {
        STAGE(kv0 + 128, 1);
        TILE(0);
        __syncthreads();
        if (kv0 + 256 < NKV) STAGE(kv0 + 256, 0);
        TILE(1);
        __syncthreads();
    }

    // normalize + store (lacc aligned with oacc: no shuffles)
#pragma unroll
    for (int mtl = 0; mtl < 2; ++mtl) {
#pragma unroll
        for (int ii = 0; ii < 4; ++ii) {
            float linv = __builtin_amdgcn_rcpf(lacc[mtl][ii]);
            int i = q0 + mtl * 16 + g * 4 + ii;
#pragma unroll
            for (int nt = 0; nt < 4; ++nt) {
                int d = nt * 16 + r;
                O[(size_t)(b * NQ + i) * DI + h * DH + d] = f2bf(oacc[mtl][nt][ii] * linv);
            }
        }
    }
}

extern "C" void kernel_launch(void* const* d_in, const int* in_sizes, int n_in,
                              void* d_out, int out_size, void* d_ws, size_t ws_size,
                              hipStream_t stream) {
    (void)in_sizes; (void)n_in; (void)out_size; (void)ws_size;
    const float* x   = (const float*)d_in[0];
    const float* ctx = (const float*)d_in[1];
    const float* Wq  = (const float*)d_in[2];
    const float* Wk  = (const float*)d_in[3];
    const float* Wv  = (const float*)d_in[4];
    const float* Wo  = (const float*)d_in[5];
    const float* bo  = (const float*)d_in[6];
    float* out = (float*)d_out;

    char* ws = (char*)d_ws;
    u16* Wqt  = (u16*)(ws);                                  // 0.5 MB
    u16* Wkvt = (u16*)(ws + (size_t)524288);                 // 1.5 MB
    u16* Wot  = (u16*)(ws + (size_t)2097152);                // 0.5 MB
    u16* Qw   = (u16*)(ws + (size_t)2621440);                // 16 MB
    u16* KVw  = (u16*)(ws + (size_t)19398656);               // 8 MB
    u16* slotC = (u16*)(ws + (size_t)27787264);              // 16 MB: xb then Ow
    u16* slotD = (u16*)(ws + (size_t)44564480);              // 6 MB: ctxb then Vtw
    u16* xb   = slotC;
    u16* Ow   = slotC;
    u16* ctxb = slotD;
    u16* Vtw  = slotD;

    k_prep<<<dim3(6912), 256, 0, stream>>>(x, xb, ctx, ctxb, Wq, Wk, Wv, Wo, Wqt, Wkvt, Wot);
    k_gemm_qkv<<<dim3(768), 256, 0, stream>>>(xb, Wqt, Qw, ctxb, Wkvt, KVw);
    k_transposeV<<<dim3(32, 2, 32), 256, 0, stream>>>(KVw, Vtw);
    k_attn<<<dim3(32, 32), 256, 0, stream>>>(Qw, KVw, Vtw, Ow);
    k_gemm_o<<<dim3(512), 256, 0, stream>>>(Ow, Wot, out, bo);
}